// Round 20
// baseline (161.127 us; speedup 1.0000x reference)
//
#include <hip/hip_runtime.h>

// LSTM-cell (h0=c0=0) + Linear, fused.  out = Lin(h(x @ W_ih^T + b)).
// x: [65536,1024] f32 -> out: [65536,1024] f32.
// R20 = R19 fused structure + R15's full-row NT store machinery.
//   R19 lesson: NT + scattered 64B stores = 20% WRITE amplification (308MB
//   for 256MB of output) — sub-line NT writes can't merge (NT bypasses L2).
//   NT requires full-line-contiguous stores (R15's +38% was NT x full 4KB rows).
//   Phase 2 now: preload h-frags for all 4 row-groups (32 VGPR, static idx),
//   then per chunk (4 row-groups x 2 col-halves): MFMA -> XOR-swizzled 32KB
//   LDS -> stream 16 rows x 2KB contiguous NT stores.
// Phase 1 + nonlin: verbatim R15 gates (h in LDS, no g_h round-trip).

typedef _Float16 f16;
typedef f16 f16x8 __attribute__((ext_vector_type(8)));
typedef float f32x4 __attribute__((ext_vector_type(4)));

#define W1S_ELEMS (32 * 10 * 64)   // f16x8 units: [ks32][gt][lane]
#define W2S_ELEMS (64 * 2 * 64)    // f16x8 units: [ct][ks2][lane]

__device__ f16x8 g_w1s[W1S_ELEMS];
__device__ f16x8 g_w2s[W2S_ELEMS];
__device__ float g_bias[160];

__device__ __forceinline__ int pack_map(int j) {
    return (j < 50) ? j : (j < 150) ? (j + 50) : -1;   // skip dead f-gate rows
}

__global__ __launch_bounds__(256) void prep_kernel(
    const float* __restrict__ W_ih, const float* __restrict__ b_ih,
    const float* __restrict__ b_hh, const float* __restrict__ W_lin)
{
    int idx = blockIdx.x * 256 + threadIdx.x;
    if (idx < W1S_ELEMS) {
        int lane = idx & 63, rest = idx >> 6;
        int gt = rest % 10, ks = rest / 10;
        int prow = gt * 16 + (lane & 15);
        int oj = pack_map(prow);
        int k0 = ks * 32 + ((lane >> 4) << 3);
        f16x8 v;
        #pragma unroll
        for (int j = 0; j < 8; ++j)
            v[j] = (f16)((oj >= 0) ? W_ih[oj * 1024 + k0 + j] : 0.f);
        g_w1s[idx] = v;
    } else if (idx < W1S_ELEMS + W2S_ELEMS) {
        int i2 = idx - W1S_ELEMS;
        int lane = i2 & 63, rest = i2 >> 6;
        int ks = rest & 1, ct = rest >> 1;
        int ocol = ct * 16 + (lane & 15);
        int k0 = ks * 32 + ((lane >> 4) << 3);
        f16x8 v;
        #pragma unroll
        for (int j = 0; j < 8; ++j) {
            int k = k0 + j;
            v[j] = (f16)((k < 50) ? W_lin[ocol * 50 + k] : 0.f);
        }
        g_w2s[i2] = v;
    } else if (idx < W1S_ELEMS + W2S_ELEMS + 160) {
        int i3 = idx - (W1S_ELEMS + W2S_ELEMS);
        int oj = pack_map(i3);
        g_bias[i3] = (oj >= 0) ? (b_ih[oj] + b_hh[oj]) : 0.f;
    }
}

// rotation swizzle for the f32 gate buffer (<=2-way banks both sides)
__device__ __forceinline__ int gaddr(int row, int col) {
    int c = col + ((row & 15) << 2);
    if (c >= 160) c -= 160;
    return row * 160 + c;
}

__device__ __forceinline__ float fast_tanh(float v) {
    float t = __expf(-2.f * v);
    return (1.f - t) / (1.f + t);
}

#define GLOAD16(gp, lp) __builtin_amdgcn_global_load_lds( \
    (const __attribute__((address_space(1))) void*)(gp),  \
    (__attribute__((address_space(3))) void*)(lp), 16, 0, 0)

// ---- fused: x -> h (LDS) -> out.  64 rows/block, grid 1024, 4 blocks/CU ----
__global__ __launch_bounds__(256, 4) void lstm_fused(
    const float* __restrict__ x, const float* __restrict__ blin,
    float* __restrict__ out)
{
    __shared__ __align__(16) char smem[40960];
    float* gs = (float*)smem;
    f16*   hs = (f16*)smem;          // [64][72] f16 after nonlin
    float* ls = (float*)smem;        // [16][512] f32 staging in phase 2

    const int tid  = threadIdx.x;
    const int lane = tid & 63;
    const int wv   = tid >> 6;
    const int lcol = lane & 15;
    const int l4   = lane >> 4;
    const long row0 = (long)blockIdx.x * 64;
    const int wrow = wv * 16;

    const int bid   = blockIdx.x;
    const int koff  = (bid * 5 + (bid >> 8) * 8) & 31;

    const int wt0 = (wv < 2) ? wv * 3 : 6 + (wv - 2) * 2;
    const int nw  = (wv < 2) ? 3 : 2;

    const int sw = ((lane & 7) ^ (lane >> 3)) << 2;
    const float* xsrc0 = x + (row0 + (2 * wv) * 8 + (lane >> 3)) * 1024 + sw;
    const float* xsrc1 = x + (row0 + (2 * wv + 1) * 8 + (lane >> 3)) * 1024 + sw;

    char* xs0 = smem + (2 * wv) * 1024;
    char* xs1 = smem + (2 * wv + 1) * 1024;

    #define STAGE(c, par) do {                                                 \
        const int c_ = (c);                                                    \
        const int p_ = (par);                                                  \
        GLOAD16(xsrc0 + c_ * 32, xs0 + p_ * 8192);                             \
        GLOAD16(xsrc1 + c_ * 32, xs1 + p_ * 8192);                             \
        _Pragma("unroll")                                                      \
        for (int wti = 0; wti < 3; ++wti)                                      \
            if (wti < nw)                                                      \
                GLOAD16((const f16x8*)g_w1s + c_ * 640 + (wt0 + wti) * 64 + lane, \
                        smem + 16384 + p_ * 10240 + (wt0 + wti) * 1024);       \
    } while (0)

    f32x4 acc[10];
    #pragma unroll
    for (int g = 0; g < 10; ++g) acc[g] = (f32x4){0.f, 0.f, 0.f, 0.f};

    STAGE(koff, 0);
    STAGE((koff + 1) & 31, 1);

    const int abyte = (wrow + lcol) * 128;
    const int au0 = ((2 * l4 + 0) ^ (lcol & 7)) << 4;
    const int au1 = ((2 * l4 + 1) ^ (lcol & 7)) << 4;

    for (int t = 0; t < 32; ++t) {
        if (t == 31)       asm volatile("s_waitcnt vmcnt(0)" ::: "memory");
        else if (wv < 2)   asm volatile("s_waitcnt vmcnt(5)" ::: "memory");
        else               asm volatile("s_waitcnt vmcnt(4)" ::: "memory");
        __builtin_amdgcn_sched_barrier(0);
        __builtin_amdgcn_s_barrier();

        const int par = t & 1;
        const char* ab = smem + par * 8192 + abyte;
        float4 qa = *(const float4*)(ab + au0);
        float4 qb = *(const float4*)(ab + au1);
        f16x8 af = { (f16)qa.x, (f16)qa.y, (f16)qa.z, (f16)qa.w,
                     (f16)qb.x, (f16)qb.y, (f16)qb.z, (f16)qb.w };
        const f16x8* wb = (const f16x8*)(smem + 16384 + par * 10240) + lane;
        #pragma unroll
        for (int g = 0; g < 10; ++g) {
            f16x8 bf = wb[g * 64];
            acc[g] = __builtin_amdgcn_mfma_f32_16x16x32_f16(af, bf, acc[g], 0, 0, 0);
        }

        asm volatile("s_waitcnt lgkmcnt(0)" ::: "memory");
        __builtin_amdgcn_sched_barrier(0);
        __builtin_amdgcn_s_barrier();
        if (t < 30) STAGE((t + 2 + koff) & 31, par);
    }

    // gates(+bias) -> swizzled LDS exchange
    #pragma unroll
    for (int g = 0; g < 10; ++g) {
        float bb = g_bias[g * 16 + lcol];
        #pragma unroll
        for (int r = 0; r < 4; ++r)
            gs[gaddr(wrow + l4 * 4 + r, g * 16 + lcol)] = acc[g][r] + bb;
    }
    __syncthreads();

    // nonlinearity -> h regs
    const int nrow = tid >> 2, sub = tid & 3;
    const int c0 = sub * 13;
    float hreg[13];
    #pragma unroll
    for (int j = 0; j < 13; ++j) {
        int c = c0 + j;
        float hv = 0.f;
        if (c < 50) {
            float iv = gs[gaddr(nrow, c)];
            float gv = gs[gaddr(nrow, 50 + c)];
            float ov = gs[gaddr(nrow, 100 + c)];
            float cv = fast_tanh(gv) / (1.f + __expf(-iv));
            hv = tanhf(cv) / (1.f + __expf(-ov));
        }
        hreg[j] = hv;
    }
    __syncthreads();

    // h -> LDS [64][72] f16 (overlays gs)
    #pragma unroll
    for (int j = 0; j < 13; ++j)
        hs[nrow * 72 + c0 + j] = (f16)hreg[j];
    if (sub == 3) {
        #pragma unroll
        for (int c = 52; c < 64; ++c) hs[nrow * 72 + c] = (f16)0.f;
    }
    __syncthreads();

    // ---- phase 2: out = h @ W2^T + b_lin; LDS-staged full-row NT stores ----
    // preload h B-frags for all 4 row-groups (static indexing; 32 VGPR)
    f16x8 bh[4][2];
    #pragma unroll
    for (int g = 0; g < 4; ++g) {
        bh[g][0] = *(const f16x8*)(hs + (g * 16 + lcol) * 72 + l4 * 8);
        bh[g][1] = *(const f16x8*)(hs + (g * 16 + lcol) * 72 + 32 + l4 * 8);
    }
    __syncthreads();                 // hs dead; ls takes over smem

    #pragma unroll
    for (int g = 0; g < 4; ++g) {
        #pragma unroll
        for (int half = 0; half < 2; ++half) {
            #pragma unroll
            for (int i = 0; i < 8; ++i) {
                int ctl = wv * 8 + i;                 // 0..31 within half
                int ct  = half * 32 + ctl;
                float4 bl = *(const float4*)(blin + ct * 16 + l4 * 4);
                f32x4 o = { bl.x, bl.y, bl.z, bl.w };
                const f16x8* w2b = g_w2s + ct * 128 + lane;
                o = __builtin_amdgcn_mfma_f32_16x16x32_f16(w2b[0],  bh[g][0], o, 0, 0, 0);
                o = __builtin_amdgcn_mfma_f32_16x16x32_f16(w2b[64], bh[g][1], o, 0, 0, 0);
                int u = ctl * 4 + l4;                 // f32x4-unit 0..127
                *(f32x4*)(ls + lcol * 512 + ((u ^ (lcol & 7)) << 2)) = o;
            }
            __syncthreads();
            #pragma unroll
            for (int it = 0; it < 8; ++it) {
                int row = it * 2 + (tid >> 7);        // 0..15
                int u = tid & 127;
                f32x4 v = *(const f32x4*)(ls + row * 512 + ((u ^ (row & 7)) << 2));
                __builtin_nontemporal_store(v,
                    (f32x4*)(out + (row0 + g * 16 + row) * 1024 + half * 512 + u * 4));
            }
            __syncthreads();
        }
    }
}

extern "C" void kernel_launch(void* const* d_in, const int* in_sizes, int n_in,
                              void* d_out, int out_size, void* d_ws, size_t ws_size,
                              hipStream_t stream) {
    const float* x     = (const float*)d_in[0];
    const float* W_ih  = (const float*)d_in[1];
    // d_in[2] = W_hh — provably unused (h_prev = 0)
    const float* b_ih  = (const float*)d_in[3];
    const float* b_hh  = (const float*)d_in[4];
    const float* W_lin = (const float*)d_in[5];
    const float* b_lin = (const float*)d_in[6];
    float* out = (float*)d_out;

    int prep_total = W1S_ELEMS + W2S_ELEMS + 160;
    prep_kernel<<<(prep_total + 255) / 256, 256, 0, stream>>>(
        W_ih, b_ih, b_hh, W_lin);

    lstm_fused<<<1024, 256, 0, stream>>>(x, b_lin, out);
}

// Round 21
// 114.168 us; speedup vs baseline: 1.4113x; 1.4113x over previous
//
#include <hip/hip_runtime.h>

// LSTM-cell (h0=c0=0) + Linear.  out = Lin(h(x @ W_ih^T + b)), f-gate dead.
// x: [65536,1024] f32 -> out: [65536,1024] f32.
// R21 = REVERT to R15 (best: 114us). Fusion falsified twice:
//   R19 (fused, scattered NT): 130.7us, WRITE 308MB (sub-line NT amplification).
//   R20 (fused, full-row NT):  161us, FETCH 198MB + WRITE 376MB — fusion itself
//   amplifies both streams (L3 thrash between read and NT-write streams).
// Split structure: gates (256MB read, 57us, 4.6TB/s) + lin (256MB NT write,
// 57us, 4.6TB/s). 114us vs 84us copy-grade floor = 73% — the residual needs
// barrier-free copy-style streaming the GEMM phases preclude.
// Lessons encoded: NT stores full-row only (R15 +38%); NT loads hurt (R16);
// cached x (L3 serves ~half); W2 register-resident; channel decorrelation koff.

typedef _Float16 f16;
typedef f16 f16x8 __attribute__((ext_vector_type(8)));
typedef float f32x4 __attribute__((ext_vector_type(4)));

#define W1S_ELEMS (32 * 10 * 64)   // f16x8 units: [ks32][gt][lane]
#define W2S_ELEMS (64 * 2 * 64)    // f16x8 units: [ct][ks2][lane]

__device__ f16x8 g_w1s[W1S_ELEMS];
__device__ f16x8 g_w2s[W2S_ELEMS];
__device__ float g_bias[160];
__device__ f16   g_h[65536L * 64];   // intermediate h (8MB)

__device__ __forceinline__ int pack_map(int j) {
    return (j < 50) ? j : (j < 150) ? (j + 50) : -1;   // skip dead f-gate rows
}

__global__ __launch_bounds__(256) void prep_kernel(
    const float* __restrict__ W_ih, const float* __restrict__ b_ih,
    const float* __restrict__ b_hh, const float* __restrict__ W_lin)
{
    int idx = blockIdx.x * 256 + threadIdx.x;
    if (idx < W1S_ELEMS) {
        int lane = idx & 63, rest = idx >> 6;
        int gt = rest % 10, ks = rest / 10;
        int prow = gt * 16 + (lane & 15);
        int oj = pack_map(prow);
        int k0 = ks * 32 + ((lane >> 4) << 3);
        f16x8 v;
        #pragma unroll
        for (int j = 0; j < 8; ++j)
            v[j] = (f16)((oj >= 0) ? W_ih[oj * 1024 + k0 + j] : 0.f);
        g_w1s[idx] = v;
    } else if (idx < W1S_ELEMS + W2S_ELEMS) {
        int i2 = idx - W1S_ELEMS;
        int lane = i2 & 63, rest = i2 >> 6;
        int ks = rest & 1, ct = rest >> 1;
        int ocol = ct * 16 + (lane & 15);
        int k0 = ks * 32 + ((lane >> 4) << 3);
        f16x8 v;
        #pragma unroll
        for (int j = 0; j < 8; ++j) {
            int k = k0 + j;
            v[j] = (f16)((k < 50) ? W_lin[ocol * 50 + k] : 0.f);
        }
        g_w2s[i2] = v;
    } else if (idx < W1S_ELEMS + W2S_ELEMS + 160) {
        int i3 = idx - (W1S_ELEMS + W2S_ELEMS);
        int oj = pack_map(i3);
        g_bias[i3] = (oj >= 0) ? (b_ih[oj] + b_hh[oj]) : 0.f;
    }
}

// rotation swizzle for the f32 gate buffer (<=2-way banks both sides)
__device__ __forceinline__ int gaddr(int row, int col) {
    int c = col + ((row & 15) << 2);
    if (c >= 160) c -= 160;
    return row * 160 + c;
}

__device__ __forceinline__ float fast_tanh(float v) {
    float t = __expf(-2.f * v);
    return (1.f - t) / (1.f + t);
}

#define GLOAD16(gp, lp) __builtin_amdgcn_global_load_lds( \
    (const __attribute__((address_space(1))) void*)(gp),  \
    (__attribute__((address_space(3))) void*)(lp), 16, 0, 0)

// ---- kernel A: x -> h (R10 phase 1 + nonlin, proven; h to g_h) -------------
__global__ __launch_bounds__(256, 4) void lstm_gates(const float* __restrict__ x)
{
    __shared__ __align__(16) char smem[40960];
    float* gs = (float*)smem;
    f16*   hs = (f16*)smem;

    const int tid  = threadIdx.x;
    const int lane = tid & 63;
    const int wv   = tid >> 6;
    const int lcol = lane & 15;
    const int l4   = lane >> 4;
    const long row0 = (long)blockIdx.x * 64;
    const int wrow = wv * 16;

    const int bid   = blockIdx.x;
    const int koff  = (bid * 5 + (bid >> 8) * 8) & 31;

    const int wt0 = (wv < 2) ? wv * 3 : 6 + (wv - 2) * 2;
    const int nw  = (wv < 2) ? 3 : 2;

    const int sw = ((lane & 7) ^ (lane >> 3)) << 2;
    const float* xsrc0 = x + (row0 + (2 * wv) * 8 + (lane >> 3)) * 1024 + sw;
    const float* xsrc1 = x + (row0 + (2 * wv + 1) * 8 + (lane >> 3)) * 1024 + sw;

    char* xs0 = smem + (2 * wv) * 1024;
    char* xs1 = smem + (2 * wv + 1) * 1024;

    #define STAGE(c, par) do {                                                 \
        const int c_ = (c);                                                    \
        const int p_ = (par);                                                  \
        GLOAD16(xsrc0 + c_ * 32, xs0 + p_ * 8192);                             \
        GLOAD16(xsrc1 + c_ * 32, xs1 + p_ * 8192);                             \
        _Pragma("unroll")                                                      \
        for (int wti = 0; wti < 3; ++wti)                                      \
            if (wti < nw)                                                      \
                GLOAD16((const f16x8*)g_w1s + c_ * 640 + (wt0 + wti) * 64 + lane, \
                        smem + 16384 + p_ * 10240 + (wt0 + wti) * 1024);       \
    } while (0)

    f32x4 acc[10];
    #pragma unroll
    for (int g = 0; g < 10; ++g) acc[g] = (f32x4){0.f, 0.f, 0.f, 0.f};

    STAGE(koff, 0);
    STAGE((koff + 1) & 31, 1);

    const int abyte = (wrow + lcol) * 128;
    const int au0 = ((2 * l4 + 0) ^ (lcol & 7)) << 4;
    const int au1 = ((2 * l4 + 1) ^ (lcol & 7)) << 4;

    for (int t = 0; t < 32; ++t) {
        if (t == 31)       asm volatile("s_waitcnt vmcnt(0)" ::: "memory");
        else if (wv < 2)   asm volatile("s_waitcnt vmcnt(5)" ::: "memory");
        else               asm volatile("s_waitcnt vmcnt(4)" ::: "memory");
        __builtin_amdgcn_sched_barrier(0);
        __builtin_amdgcn_s_barrier();

        const int par = t & 1;
        const char* ab = smem + par * 8192 + abyte;
        float4 qa = *(const float4*)(ab + au0);
        float4 qb = *(const float4*)(ab + au1);
        f16x8 af = { (f16)qa.x, (f16)qa.y, (f16)qa.z, (f16)qa.w,
                     (f16)qb.x, (f16)qb.y, (f16)qb.z, (f16)qb.w };
        const f16x8* wb = (const f16x8*)(smem + 16384 + par * 10240) + lane;
        #pragma unroll
        for (int g = 0; g < 10; ++g) {
            f16x8 bf = wb[g * 64];
            acc[g] = __builtin_amdgcn_mfma_f32_16x16x32_f16(af, bf, acc[g], 0, 0, 0);
        }

        asm volatile("s_waitcnt lgkmcnt(0)" ::: "memory");
        __builtin_amdgcn_sched_barrier(0);
        __builtin_amdgcn_s_barrier();
        if (t < 30) STAGE((t + 2 + koff) & 31, par);
    }

    // gates(+bias) -> swizzled LDS exchange
    #pragma unroll
    for (int g = 0; g < 10; ++g) {
        float bb = g_bias[g * 16 + lcol];
        #pragma unroll
        for (int r = 0; r < 4; ++r)
            gs[gaddr(wrow + l4 * 4 + r, g * 16 + lcol)] = acc[g][r] + bb;
    }
    __syncthreads();

    const int nrow = tid >> 2, sub = tid & 3;
    const int c0 = sub * 13;
    float hreg[13];
    #pragma unroll
    for (int j = 0; j < 13; ++j) {
        int c = c0 + j;
        float hv = 0.f;
        if (c < 50) {
            float iv = gs[gaddr(nrow, c)];
            float gv = gs[gaddr(nrow, 50 + c)];
            float ov = gs[gaddr(nrow, 100 + c)];
            float cv = fast_tanh(gv) / (1.f + __expf(-iv));
            hv = fast_tanh(cv) / (1.f + __expf(-ov));
        }
        hreg[j] = hv;
    }
    __syncthreads();

    #pragma unroll
    for (int j = 0; j < 13; ++j)
        hs[nrow * 72 + c0 + j] = (f16)hreg[j];
    if (sub == 3) {
        #pragma unroll
        for (int c = 52; c < 64; ++c) hs[nrow * 72 + c] = (f16)0.f;
    }
    __syncthreads();

    // h tile -> g_h (vectorized 2x16B per thread, coalesced)
    {
        const int hr = tid >> 2;                 // 0..63
        const int uu = (tid & 3) * 2;            // f16x8 unit 0,2,4,6
        f16x8 v0 = *(const f16x8*)(hs + hr * 72 + uu * 8);
        f16x8 v1 = *(const f16x8*)(hs + hr * 72 + uu * 8 + 8);
        *(f16x8*)(g_h + (row0 + hr) * 64 + uu * 8)     = v0;
        *(f16x8*)(g_h + (row0 + hr) * 64 + uu * 8 + 8) = v1;
    }
}

// ---- kernel B: register-W2, LDS transpose, full-row NONTEMPORAL stores -----
__global__ __launch_bounds__(1024) void lstm_lin(
    const float* __restrict__ blin, float* __restrict__ out)
{
    __shared__ __align__(16) float ls[16 * 1024];      // 64KB out-tile staging
    __shared__ __align__(16) f16 hs_l[2][16 * 72];     // h tile double buffer

    const int tid  = threadIdx.x;
    const int lane = tid & 63;
    const int wv   = tid >> 6;        // 0..15
    const int lcol = lane & 15;
    const int l4   = lane >> 4;
    const long r0  = (long)blockIdx.x * 256;

    // per-wave register-resident W2 fragments + bias (loaded ONCE)
    f16x8 w2r0[4], w2r1[4];
    float4 blr[4];
    #pragma unroll
    for (int i = 0; i < 4; ++i) {
        int ct = wv * 4 + i;
        w2r0[i] = g_w2s[ct * 128 + lane];
        w2r1[i] = g_w2s[ct * 128 + 64 + lane];
        blr[i]  = *(const float4*)(blin + ct * 16 + l4 * 4);
    }

    // stage h tile 0
    if (tid < 128) {
        int row = tid >> 3, u = tid & 7;
        *(f16x8*)(&hs_l[0][row * 72 + u * 8]) =
            *(const f16x8*)(g_h + (r0 + row) * 64 + u * 8);
    }
    __syncthreads();

    for (int rt = 0; rt < 16; ++rt) {
        const int cur = rt & 1;
        f16x8 bh0 = *(const f16x8*)(&hs_l[cur][lcol * 72 + l4 * 8]);
        f16x8 bh1 = *(const f16x8*)(&hs_l[cur][lcol * 72 + 32 + l4 * 8]);
        #pragma unroll
        for (int i = 0; i < 4; ++i) {
            int ct = wv * 4 + i;
            f32x4 o = { blr[i].x, blr[i].y, blr[i].z, blr[i].w };
            o = __builtin_amdgcn_mfma_f32_16x16x32_f16(w2r0[i], bh0, o, 0, 0, 0);
            o = __builtin_amdgcn_mfma_f32_16x16x32_f16(w2r1[i], bh1, o, 0, 0, 0);
            // D lane: out[row=lcol][ct*16 + l4*4 + r]; unit = ct*4+l4 (16B)
            int u = (ct * 4 + l4) ^ (lcol & 7);          // bank swizzle
            *(f32x4*)(ls + lcol * 1024 + u * 4) = o;
        }
        __syncthreads();
        if (rt < 15 && tid < 128) {   // stage next h tile under the copy phase
            int row = tid >> 3, u = tid & 7;
            *(f16x8*)(&hs_l[cur ^ 1][row * 72 + u * 8]) =
                *(const f16x8*)(g_h + (r0 + (rt + 1) * 16 + row) * 64 + u * 8);
        }
        {   // copy: wave wv streams its full 4KB row; NONTEMPORAL stores
            float* orow = out + (r0 + rt * 16 + wv) * 1024;
            #pragma unroll
            for (int j = 0; j < 4; ++j) {
                int u = (j * 64 + lane) ^ (wv & 7);
                f32x4 v = *(const f32x4*)(ls + wv * 1024 + u * 4);
                __builtin_nontemporal_store(v, (f32x4*)(orow + j * 256 + lane * 4));
            }
        }
        __syncthreads();
    }
}

extern "C" void kernel_launch(void* const* d_in, const int* in_sizes, int n_in,
                              void* d_out, int out_size, void* d_ws, size_t ws_size,
                              hipStream_t stream) {
    const float* x     = (const float*)d_in[0];
    const float* W_ih  = (const float*)d_in[1];
    // d_in[2] = W_hh — provably unused (h_prev = 0)
    const float* b_ih  = (const float*)d_in[3];
    const float* b_hh  = (const float*)d_in[4];
    const float* W_lin = (const float*)d_in[5];
    const float* b_lin = (const float*)d_in[6];
    float* out = (float*)d_out;

    int prep_total = W1S_ELEMS + W2S_ELEMS + 160;
    prep_kernel<<<(prep_total + 255) / 256, 256, 0, stream>>>(
        W_ih, b_ih, b_hh, W_lin);

    lstm_gates<<<1024, 256, 0, stream>>>(x);
    lstm_lin<<<256, 1024, 0, stream>>>(b_lin, out);
}